// Round 9
// baseline (76.890 us; speedup 1.0000x reference)
//
#include <hip/hip_runtime.h>
#include <hip/hip_bf16.h>

#define B_   8
#define LQ_  128
#define LM_  512
#define D_   512
#define H_   256
#define MASKVAL -1e24f
#define PRESCALE 2.88539008177792681f  // 2*log2(e): exp2(PRESCALE*x) = e^(2x)

typedef __attribute__((ext_vector_type(8))) short bf16x8;
typedef __attribute__((ext_vector_type(4))) float f32x4;

__device__ __forceinline__ ushort f2bf(float x) {
    return __builtin_bit_cast(ushort, __float2bfloat16(x));
}

// ---------------- MFMA projection GEMM (bf16 inputs, f32 accum) ----------------
// Epilogue stores E = exp2(PRESCALE * (X@W + bias)) so the attention kernel
// computes sigma(q+k) = rcp(Eq*Ek + 1) with ONE transcendental per element.
#define PBM 32
#define PBN 32
#define PBK 64
#define PLDK 88   // padded k-stride (ushorts) = 176 B: 16B-aligned, 2-way banks

__global__ __launch_bounds__(256) void proj_mfma(
    const float* __restrict__ query, const float* __restrict__ memory,
    const float* __restrict__ Wq, const float* __restrict__ Wm,
    const float* __restrict__ bq,
    float* __restrict__ qp, float* __restrict__ kp)
{
    __shared__ ushort As[PBM][PLDK];
    __shared__ ushort Bs[PBN][PLDK];   // stores W^T tile: Bs[n][k]

    const int mtile = blockIdx.x % 160;
    const int ntile = blockIdx.x / 160;
    const int n0 = ntile * PBN;
    const bool is_q = (mtile < 32);
    const float* X = is_q ? (query  + (size_t)mtile * PBM * D_)
                          : (memory + (size_t)(mtile - 32) * PBM * D_);
    const float* W = is_q ? Wq : Wm;
    float* out     = is_q ? (qp + (size_t)mtile * PBM * H_)
                          : (kp + (size_t)(mtile - 32) * PBM * H_);

    const int t = threadIdx.x;
    const int lane = t & 63, w = t >> 6;
    const int wm = (w & 1) * 16, wn = (w >> 1) * 16;

    const int ar  = t >> 4;   // A staging row
    const int akq = t & 15;   // A k-quad

    const int frow = lane & 15;
    const int fkof = (lane >> 4) * 8;

    f32x4 acc = {0.f, 0.f, 0.f, 0.f};

    for (int k0 = 0; k0 < D_; k0 += PBK) {
#pragma unroll
        for (int p = 0; p < 2; ++p) {
            const int row = ar + p * 16;
            const float4 x4 = *(const float4*)(X + (size_t)row * D_ + k0 + akq * 4);
            ushort4 u4;
            u4.x = f2bf(x4.x); u4.y = f2bf(x4.y); u4.z = f2bf(x4.z); u4.w = f2bf(x4.w);
            *(ushort4*)&As[row][akq * 4] = u4;
        }
#pragma unroll
        for (int p = 0; p < 2; ++p) {
            const int L  = t + p * 256;   // 0..511
            const int kk = L >> 3;        // k-row 0..63
            const int f4 = L & 7;         // float4 slot
            const float4 w4 = *(const float4*)(W + (size_t)(k0 + kk) * H_ + n0 + f4 * 4);
            Bs[f4 * 4 + 0][kk] = f2bf(w4.x);
            Bs[f4 * 4 + 1][kk] = f2bf(w4.y);
            Bs[f4 * 4 + 2][kk] = f2bf(w4.z);
            Bs[f4 * 4 + 3][kk] = f2bf(w4.w);
        }
        __syncthreads();
#pragma unroll
        for (int ks = 0; ks < PBK; ks += 32) {
            bf16x8 a = *(const bf16x8*)&As[wm + frow][ks + fkof];
            bf16x8 b = *(const bf16x8*)&Bs[wn + frow][ks + fkof];
            acc = __builtin_amdgcn_mfma_f32_16x16x32_bf16(a, b, acc, 0, 0, 0);
        }
        __syncthreads();
    }

    const int col  = n0 + wn + (lane & 15);
    const int rloc = wm + (lane >> 4) * 4;
    const float bias = is_q ? bq[col] : 0.0f;
#pragma unroll
    for (int r = 0; r < 4; ++r)
        out[(size_t)(rloc + r) * H_ + col] =
            __builtin_amdgcn_exp2f((acc[r] + bias) * PRESCALE);
}

// ---------------- fused score/softmax/PV ----------------
// One block = (b, 4 q). 1024 threads = 16 waves, 256 blocks.
// Phase 1: thread PAIR owns one active m (i = t>>1); each thread handles 2 q
// (qh = t&1 -> q in {qh, qh+2}) and walks the kp row with contiguous float4
// loads. NO LDS reads, NO shuffles, NO divergence in the hot loop; Eq rows
// (4 KB) + v (1 KB) stay L1-hot; pair-shared kp lines keep the live working
// set at 2 KB/wave.
__global__ __launch_bounds__(1024, 4) void attn_kernel(
    const float* __restrict__ qp,      // [1024][256] = Eq
    const float* __restrict__ kp,      // [4096][256] = Ek
    const float* __restrict__ memory,  // [8][512][512]
    const int*   __restrict__ mask,    // [8][512]
    const float* __restrict__ v,       // [256]
    float* __restrict__ out_wm,        // [1024][512]
    float* __restrict__ out_w)         // [1024][512]
{
    __shared__ float scores[4][512];   // 8 KB
    __shared__ int   mlist[512];       // 2 KB
    __shared__ int   nact_sh;
    __shared__ float sv_sh;

    const int t = threadIdx.x;
    const int b  = blockIdx.x & 7;     // all blocks of batch b -> XCD b
    const int qg = blockIdx.x >> 3;    // 0..31
    const int rowbase = b * LQ_ + qg * 4;
    const int w = t >> 6, lane = t & 63;

    ((float2*)&scores[0][0])[t] = make_float2(MASKVAL, MASKVAL);

    if (w == 14) {                      // wave 14: sv = sum(v)
        const float4 c = *(const float4*)(v + lane * 4);
        float s = c.x + c.y + c.z + c.w;
        s += __shfl_xor(s, 1);  s += __shfl_xor(s, 2);
        s += __shfl_xor(s, 4);  s += __shfl_xor(s, 8);
        s += __shfl_xor(s, 16); s += __shfl_xor(s, 32);
        if (lane == 0) sv_sh = s;
    }
    if (w == 15) {                      // wave 15: compact active-m list
        unsigned base = 0;
        for (int it = 0; it < 8; ++it) {
            int m = it * 64 + lane;
            int act = (mask[b * 512 + m] == 0);
            unsigned long long bal = __ballot(act);
            if (act) {
                int pos = __popcll(bal & ((1ull << lane) - 1ull));
                mlist[base + pos] = m;
            }
            base += __popcll(bal);
        }
        if (lane == 0) nact_sh = (int)base;
    }
    __syncthreads();
    const int nact = nact_sh;
    const float sv = sv_sh;

    // ---- phase 1: scores[q][m] = sv - 2 * sum_h v[h] * rcp(Eq*Ek + 1) ----
    {
        const int i  = t >> 1;             // mlist slot 0..511 (covers nact<=512)
        const int qh = t & 1;
        const bool active = i < nact;
        const int m = mlist[active ? i : 0] & 511;
        const float* kr  = kp + (size_t)(b * 512 + m) * 256;
        const float* q0r = qp + (size_t)(rowbase + qh) * 256;
        const float* q1r = q0r + 2 * 256;
        float acc0 = 0.f, acc1 = 0.f;
#pragma unroll 2
        for (int h4 = 0; h4 < 64; ++h4) {
            const float4 ek = *(const float4*)(kr  + h4 * 4);
            const float4 e0 = *(const float4*)(q0r + h4 * 4);
            const float4 e1 = *(const float4*)(q1r + h4 * 4);
            const float4 vv = *(const float4*)(v   + h4 * 4);
            acc0 = fmaf(vv.x, __builtin_amdgcn_rcpf(fmaf(e0.x, ek.x, 1.f)), acc0);
            acc1 = fmaf(vv.x, __builtin_amdgcn_rcpf(fmaf(e1.x, ek.x, 1.f)), acc1);
            acc0 = fmaf(vv.y, __builtin_amdgcn_rcpf(fmaf(e0.y, ek.y, 1.f)), acc0);
            acc1 = fmaf(vv.y, __builtin_amdgcn_rcpf(fmaf(e1.y, ek.y, 1.f)), acc1);
            acc0 = fmaf(vv.z, __builtin_amdgcn_rcpf(fmaf(e0.z, ek.z, 1.f)), acc0);
            acc1 = fmaf(vv.z, __builtin_amdgcn_rcpf(fmaf(e1.z, ek.z, 1.f)), acc1);
            acc0 = fmaf(vv.w, __builtin_amdgcn_rcpf(fmaf(e0.w, ek.w, 1.f)), acc0);
            acc1 = fmaf(vv.w, __builtin_amdgcn_rcpf(fmaf(e1.w, ek.w, 1.f)), acc1);
        }
        if (active) {
            scores[qh][m]     = fmaf(-2.f, acc0, sv);
            scores[qh + 2][m] = fmaf(-2.f, acc1, sv);
        }
    }
    __syncthreads();

    // ---- phase 2: softmax per q (waves 0..3) ----
    if (w < 4) {
        const int q = w, row = rowbase + q;
        float s[8], e[8];
        float mx = -INFINITY;
#pragma unroll
        for (int k = 0; k < 8; ++k) { s[k] = scores[q][lane + 64 * k]; mx = fmaxf(mx, s[k]); }
#pragma unroll
        for (int off = 32; off >= 1; off >>= 1) mx = fmaxf(mx, __shfl_xor(mx, off));
        float sum = 0.0f;
#pragma unroll
        for (int k = 0; k < 8; ++k) {
            e[k] = __builtin_amdgcn_exp2f((s[k] - mx) * 1.44269504088896341f);
            sum += e[k];
        }
#pragma unroll
        for (int off = 32; off >= 1; off >>= 1) sum += __shfl_xor(sum, off);
        float rs = __builtin_amdgcn_rcpf(sum);
#pragma unroll
        for (int k = 0; k < 8; ++k) {
            float wt = e[k] * rs;
            scores[q][lane + 64 * k] = wt;
            out_w[(size_t)row * 512 + lane + 64 * k] = wt;
        }
    }
    __syncthreads();

    // ---- phase 3: weighted_memory; d = t&511, 2 q per thread, 4-deep MLP ----
    {
        const int d  = t & 511;
        const int qh = t >> 9;             // 0 or 1
        const float* mb = memory + (size_t)b * 512 * 512 + d;
        const float* s0 = scores[qh * 2 + 0];
        const float* s1 = scores[qh * 2 + 1];
        float a0 = 0.f, a1 = 0.f;
        int i = 0;
        for (; i + 4 <= nact; i += 4) {
            const int m0 = mlist[i], m1 = mlist[i + 1], m2 = mlist[i + 2], m3 = mlist[i + 3];
            const float v0 = mb[(size_t)m0 * 512];
            const float v1 = mb[(size_t)m1 * 512];
            const float v2 = mb[(size_t)m2 * 512];
            const float v3 = mb[(size_t)m3 * 512];
            a0 = fmaf(s0[m3], v3, fmaf(s0[m2], v2, fmaf(s0[m1], v1, fmaf(s0[m0], v0, a0))));
            a1 = fmaf(s1[m3], v3, fmaf(s1[m2], v2, fmaf(s1[m1], v1, fmaf(s1[m0], v0, a1))));
        }
        for (; i < nact; ++i) {
            const int m0 = mlist[i];
            const float v0 = mb[(size_t)m0 * 512];
            a0 = fmaf(s0[m0], v0, a0);
            a1 = fmaf(s1[m0], v0, a1);
        }
        out_wm[(size_t)(rowbase + qh * 2 + 0) * 512 + d] = a0;
        out_wm[(size_t)(rowbase + qh * 2 + 1) * 512 + d] = a1;
    }
}

extern "C" void kernel_launch(void* const* d_in, const int* in_sizes, int n_in,
                              void* d_out, int out_size, void* d_ws, size_t ws_size,
                              hipStream_t stream) {
    const float* query  = (const float*)d_in[0];
    const float* memory = (const float*)d_in[1];
    const int*   mask   = (const int*)  d_in[2];
    const float* Wq     = (const float*)d_in[3];
    const float* bq     = (const float*)d_in[4];
    const float* Wm     = (const float*)d_in[5];
    const float* v      = (const float*)d_in[6];

    float* out_wm = (float*)d_out;                         // [1024][512]
    float* out_w  = out_wm + (size_t)B_ * LQ_ * D_;        // [1024][512]

    float* qp = (float*)d_ws;                              // [1024][256] = Eq
    float* kp = qp + (size_t)B_ * LQ_ * H_;                // [4096][256] = Ek

    hipLaunchKernelGGL(proj_mfma, dim3(160 * (H_ / PBN)), dim3(256), 0, stream,
                       query, memory, Wq, Wm, bq, qp, kp);
    hipLaunchKernelGGL(attn_kernel, dim3(B_ * (LQ_ / 4)), dim3(1024), 0, stream,
                       qp, kp, memory, mask, v, out_wm, out_w);
}

// Round 10
// 48.124 us; speedup vs baseline: 1.5978x; 1.5978x over previous
//
#include <hip/hip_runtime.h>
#include <hip/hip_bf16.h>

#define B_   8
#define LQ_  128
#define LM_  512
#define D_   512
#define H_   256
#define MASKVAL -1e24f
#define PRESCALE 2.88539008177792681f  // 2*log2(e): exp2(PRESCALE*x) = e^(2x)

typedef __attribute__((ext_vector_type(8))) short bf16x8;
typedef __attribute__((ext_vector_type(4))) float f32x4;

__device__ __forceinline__ ushort f2bf(float x) {
    return __builtin_bit_cast(ushort, __float2bfloat16(x));
}

// ---------------- MFMA projection GEMM (bf16 inputs, f32 accum) ----------------
// Epilogue stores E = exp2(PRESCALE * (X@W + bias)) so the attention kernel
// computes sigma(q+k) = rcp(Eq*Ek + 1) with ONE transcendental per element.
#define PBM 32
#define PBN 32
#define PBK 64
#define PLDK 88   // padded k-stride (ushorts) = 176 B: 16B-aligned, 2-way banks

__global__ __launch_bounds__(256) void proj_mfma(
    const float* __restrict__ query, const float* __restrict__ memory,
    const float* __restrict__ Wq, const float* __restrict__ Wm,
    const float* __restrict__ bq,
    float* __restrict__ qp, float* __restrict__ kp)
{
    __shared__ ushort As[PBM][PLDK];
    __shared__ ushort Bs[PBN][PLDK];   // stores W^T tile: Bs[n][k]

    const int mtile = blockIdx.x % 160;
    const int ntile = blockIdx.x / 160;
    const int n0 = ntile * PBN;
    const bool is_q = (mtile < 32);
    const float* X = is_q ? (query  + (size_t)mtile * PBM * D_)
                          : (memory + (size_t)(mtile - 32) * PBM * D_);
    const float* W = is_q ? Wq : Wm;
    float* out     = is_q ? (qp + (size_t)mtile * PBM * H_)
                          : (kp + (size_t)(mtile - 32) * PBM * H_);

    const int t = threadIdx.x;
    const int lane = t & 63, w = t >> 6;
    const int wm = (w & 1) * 16, wn = (w >> 1) * 16;

    const int ar  = t >> 4;   // A staging row
    const int akq = t & 15;   // A k-quad

    const int frow = lane & 15;
    const int fkof = (lane >> 4) * 8;

    f32x4 acc = {0.f, 0.f, 0.f, 0.f};

    for (int k0 = 0; k0 < D_; k0 += PBK) {
#pragma unroll
        for (int p = 0; p < 2; ++p) {
            const int row = ar + p * 16;
            const float4 x4 = *(const float4*)(X + (size_t)row * D_ + k0 + akq * 4);
            ushort4 u4;
            u4.x = f2bf(x4.x); u4.y = f2bf(x4.y); u4.z = f2bf(x4.z); u4.w = f2bf(x4.w);
            *(ushort4*)&As[row][akq * 4] = u4;
        }
#pragma unroll
        for (int p = 0; p < 2; ++p) {
            const int L  = t + p * 256;   // 0..511
            const int kk = L >> 3;        // k-row 0..63
            const int f4 = L & 7;         // float4 slot
            const float4 w4 = *(const float4*)(W + (size_t)(k0 + kk) * H_ + n0 + f4 * 4);
            Bs[f4 * 4 + 0][kk] = f2bf(w4.x);
            Bs[f4 * 4 + 1][kk] = f2bf(w4.y);
            Bs[f4 * 4 + 2][kk] = f2bf(w4.z);
            Bs[f4 * 4 + 3][kk] = f2bf(w4.w);
        }
        __syncthreads();
#pragma unroll
        for (int ks = 0; ks < PBK; ks += 32) {
            bf16x8 a = *(const bf16x8*)&As[wm + frow][ks + fkof];
            bf16x8 b = *(const bf16x8*)&Bs[wn + frow][ks + fkof];
            acc = __builtin_amdgcn_mfma_f32_16x16x32_bf16(a, b, acc, 0, 0, 0);
        }
        __syncthreads();
    }

    const int col  = n0 + wn + (lane & 15);
    const int rloc = wm + (lane >> 4) * 4;
    const float bias = is_q ? bq[col] : 0.0f;
#pragma unroll
    for (int r = 0; r < 4; ++r)
        out[(size_t)(rloc + r) * H_ + col] =
            __builtin_amdgcn_exp2f((acc[r] + bias) * PRESCALE);
}

// ---------------- fused score/softmax/PV ----------------
// One block = (b, 4 q). 512 threads = 8 waves, 256 blocks (1/CU).
// q[4][16h] and v[16h] live in REGISTERS (pinned with empty asm so the
// compiler cannot sink the loads back into the m-loop — the R4/R5/R9 trap).
// h-mapping h = j*64 + lane16*4 + c keeps k-row loads fully coalesced.
// Each 16-lane group owns one m per iteration; k prefetched one iter ahead.
#define PIN4(X) asm volatile("" : "+v"(X.x), "+v"(X.y), "+v"(X.z), "+v"(X.w))

__global__ __launch_bounds__(512, 2) void attn_kernel(
    const float* __restrict__ qp,      // [1024][256] = Eq
    const float* __restrict__ kp,      // [4096][256] = Ek
    const float* __restrict__ memory,  // [8][512][512]
    const int*   __restrict__ mask,    // [8][512]
    const float* __restrict__ v,       // [256]
    float* __restrict__ out_wm,        // [1024][512]
    float* __restrict__ out_w)         // [1024][512]
{
    __shared__ float scores[4][512];   // 8 KB
    __shared__ int   mlist[512];       // 2 KB
    __shared__ int   nact_sh;
    __shared__ float sv_sh;

    const int t = threadIdx.x;
    const int b  = blockIdx.x & 7;     // all blocks of batch b -> XCD b
    const int qg = blockIdx.x >> 3;    // 0..31
    const int rowbase = b * LQ_ + qg * 4;
    const int w = t >> 6, lane = t & 63;

    ((float4*)&scores[0][0])[t] = make_float4(MASKVAL, MASKVAL, MASKVAL, MASKVAL);

    if (w == 6) {                       // wave 6: sv = sum(v)
        const float4 c = *(const float4*)(v + lane * 4);
        float s = c.x + c.y + c.z + c.w;
        s += __shfl_xor(s, 1);  s += __shfl_xor(s, 2);
        s += __shfl_xor(s, 4);  s += __shfl_xor(s, 8);
        s += __shfl_xor(s, 16); s += __shfl_xor(s, 32);
        if (lane == 0) sv_sh = s;
    }
    if (w == 7) {                       // wave 7: compact active-m list
        unsigned base = 0;
        for (int it = 0; it < 8; ++it) {
            int m = it * 64 + lane;
            int act = (mask[b * 512 + m] == 0);
            unsigned long long bal = __ballot(act);
            if (act) {
                int pos = __popcll(bal & ((1ull << lane) - 1ull));
                mlist[base + pos] = m;
            }
            base += __popcll(bal);
        }
        if (lane == 0) nact_sh = (int)base;
    }

    // load q/v fragments into registers (h = j*64 + lane16*4 + c)
    const int lane16 = lane & 15, mg = lane >> 4;
    const int col = lane16 * 4;
    float4 qreg[4][4], vreg[4];
#pragma unroll
    for (int j = 0; j < 4; ++j) {
        vreg[j] = *(const float4*)(v + j * 64 + col);
        PIN4(vreg[j]);
    }
#pragma unroll
    for (int q = 0; q < 4; ++q)
#pragma unroll
        for (int j = 0; j < 4; ++j) {
            qreg[q][j] = *(const float4*)(qp + (size_t)(rowbase + q) * 256 + j * 64 + col);
            PIN4(qreg[q][j]);
        }

    __syncthreads();
    const int nact = nact_sh;
    const float sv = sv_sh;

    // ---- phase 1: scores[q][m] = sv - 2 * sum_h v[h] * rcp(Eq*Ek + 1) ----
    if (nact > 0) {
        const float* kbase = kp + (size_t)b * 512 * 256 + col;
        int i = w * 4 + mg;                         // this group's slot
        const int last = nact - 1;
        int mcur = mlist[i <= last ? i : last];
        float4 k0 = *(const float4*)(kbase + (size_t)mcur * 256);
        float4 k1 = *(const float4*)(kbase + (size_t)mcur * 256 + 64);
        float4 k2 = *(const float4*)(kbase + (size_t)mcur * 256 + 128);
        float4 k3 = *(const float4*)(kbase + (size_t)mcur * 256 + 192);
        const int nit = (nact + 31) >> 5;           // 32 m per block-iter
        for (int it = 0; it < nit; ++it) {
            const int inext = i + 32;
            const int mnext = mlist[inext <= last ? inext : last];
            float4 n0, n1, n2, n3;
            if (it + 1 < nit) {                     // prefetch next k row
                n0 = *(const float4*)(kbase + (size_t)mnext * 256);
                n1 = *(const float4*)(kbase + (size_t)mnext * 256 + 64);
                n2 = *(const float4*)(kbase + (size_t)mnext * 256 + 128);
                n3 = *(const float4*)(kbase + (size_t)mnext * 256 + 192);
            }
            float acc0 = 0.f, acc1 = 0.f, acc2 = 0.f, acc3 = 0.f;
#define COMP(J, C) { \
            const float kk = k##J.C, vv = vreg[J].C; \
            acc0 = fmaf(vv, __builtin_amdgcn_rcpf(fmaf(qreg[0][J].C, kk, 1.f)), acc0); \
            acc1 = fmaf(vv, __builtin_amdgcn_rcpf(fmaf(qreg[1][J].C, kk, 1.f)), acc1); \
            acc2 = fmaf(vv, __builtin_amdgcn_rcpf(fmaf(qreg[2][J].C, kk, 1.f)), acc2); \
            acc3 = fmaf(vv, __builtin_amdgcn_rcpf(fmaf(qreg[3][J].C, kk, 1.f)), acc3); }
            COMP(0, x) COMP(0, y) COMP(0, z) COMP(0, w)
            COMP(1, x) COMP(1, y) COMP(1, z) COMP(1, w)
            COMP(2, x) COMP(2, y) COMP(2, z) COMP(2, w)
            COMP(3, x) COMP(3, y) COMP(3, z) COMP(3, w)
#undef COMP
#define RED(X) X += __shfl_xor(X, 1); X += __shfl_xor(X, 2); \
               X += __shfl_xor(X, 4); X += __shfl_xor(X, 8);
            RED(acc0) RED(acc1) RED(acc2) RED(acc3)
#undef RED
            if (lane16 == 0 && i < nact) {
                scores[0][mcur] = fmaf(-2.f, acc0, sv);
                scores[1][mcur] = fmaf(-2.f, acc1, sv);
                scores[2][mcur] = fmaf(-2.f, acc2, sv);
                scores[3][mcur] = fmaf(-2.f, acc3, sv);
            }
            i = inext; mcur = mnext;
            k0 = n0; k1 = n1; k2 = n2; k3 = n3;
        }
    }
    __syncthreads();

    // ---- phase 2: softmax per q (waves 0..3) ----
    if (w < 4) {
        const int q = w, row = rowbase + q;
        float s[8], e[8];
        float mx = -INFINITY;
#pragma unroll
        for (int k = 0; k < 8; ++k) { s[k] = scores[q][lane + 64 * k]; mx = fmaxf(mx, s[k]); }
#pragma unroll
        for (int off = 32; off >= 1; off >>= 1) mx = fmaxf(mx, __shfl_xor(mx, off));
        float sum = 0.0f;
#pragma unroll
        for (int k = 0; k < 8; ++k) {
            e[k] = __builtin_amdgcn_exp2f((s[k] - mx) * 1.44269504088896341f);
            sum += e[k];
        }
#pragma unroll
        for (int off = 32; off >= 1; off >>= 1) sum += __shfl_xor(sum, off);
        float rs = __builtin_amdgcn_rcpf(sum);
#pragma unroll
        for (int k = 0; k < 8; ++k) {
            float wt = e[k] * rs;
            scores[q][lane + 64 * k] = wt;
            out_w[(size_t)row * 512 + lane + 64 * k] = wt;
        }
    }
    __syncthreads();

    // ---- phase 3: weighted_memory; d = t, all 4 q per thread, 4-deep MLP ----
    {
        const int d = t;
        const float* mb = memory + (size_t)b * 512 * 512 + d;
        float a0 = 0.f, a1 = 0.f, a2 = 0.f, a3 = 0.f;
        int i = 0;
        for (; i + 4 <= nact; i += 4) {
            const int m0 = mlist[i], m1 = mlist[i + 1], m2 = mlist[i + 2], m3 = mlist[i + 3];
            const float v0 = mb[(size_t)m0 * 512];
            const float v1 = mb[(size_t)m1 * 512];
            const float v2 = mb[(size_t)m2 * 512];
            const float v3 = mb[(size_t)m3 * 512];
            a0 = fmaf(scores[0][m3], v3, fmaf(scores[0][m2], v2, fmaf(scores[0][m1], v1, fmaf(scores[0][m0], v0, a0))));
            a1 = fmaf(scores[1][m3], v3, fmaf(scores[1][m2], v2, fmaf(scores[1][m1], v1, fmaf(scores[1][m0], v0, a1))));
            a2 = fmaf(scores[2][m3], v3, fmaf(scores[2][m2], v2, fmaf(scores[2][m1], v1, fmaf(scores[2][m0], v0, a2))));
            a3 = fmaf(scores[3][m3], v3, fmaf(scores[3][m2], v2, fmaf(scores[3][m1], v1, fmaf(scores[3][m0], v0, a3))));
        }
        for (; i < nact; ++i) {
            const int m0 = mlist[i];
            const float v0 = mb[(size_t)m0 * 512];
            a0 = fmaf(scores[0][m0], v0, a0);
            a1 = fmaf(scores[1][m0], v0, a1);
            a2 = fmaf(scores[2][m0], v0, a2);
            a3 = fmaf(scores[3][m0], v0, a3);
        }
        out_wm[(size_t)(rowbase + 0) * 512 + d] = a0;
        out_wm[(size_t)(rowbase + 1) * 512 + d] = a1;
        out_wm[(size_t)(rowbase + 2) * 512 + d] = a2;
        out_wm[(size_t)(rowbase + 3) * 512 + d] = a3;
    }
}

extern "C" void kernel_launch(void* const* d_in, const int* in_sizes, int n_in,
                              void* d_out, int out_size, void* d_ws, size_t ws_size,
                              hipStream_t stream) {
    const float* query  = (const float*)d_in[0];
    const float* memory = (const float*)d_in[1];
    const int*   mask   = (const int*)  d_in[2];
    const float* Wq     = (const float*)d_in[3];
    const float* bq     = (const float*)d_in[4];
    const float* Wm     = (const float*)d_in[5];
    const float* v      = (const float*)d_in[6];

    float* out_wm = (float*)d_out;                         // [1024][512]
    float* out_w  = out_wm + (size_t)B_ * LQ_ * D_;        // [1024][512]

    float* qp = (float*)d_ws;                              // [1024][256] = Eq
    float* kp = qp + (size_t)B_ * LQ_ * H_;                // [4096][256] = Ek

    hipLaunchKernelGGL(proj_mfma, dim3(160 * (H_ / PBN)), dim3(256), 0, stream,
                       query, memory, Wq, Wm, bq, qp, kp);
    hipLaunchKernelGGL(attn_kernel, dim3(B_ * (LQ_ / 4)), dim3(512), 0, stream,
                       qp, kp, memory, mask, v, out_wm, out_w);
}